// Round 10
// baseline (349.659 us; speedup 1.0000x reference)
//
#include <hip/hip_runtime.h>
#include <math.h>

#define NB 32          // MAX_NODES
#define BATCH 16384
#define WPB 4          // waves per block; each wave owns TWO matrices
#define TPB (WPB * 64) // 256 threads
#define MPB (WPB * 2)  // 8 matrices per block

// ws layout (16 B, zeroed by hipMemsetAsync): [0]=bce_sum [1]=mask_sum [2]=phys_sum [3]=unused

// ---- DPP cross-lane helpers (VALU pipe) ----
template<int CTRL>
__device__ __forceinline__ float dpp_add(float v) {
    const int s = __float_as_int(v);
    const int r = __builtin_amdgcn_update_dpp(s, s, CTRL, 0xF, 0xF, false);
    return v + __int_as_float(r);
}
template<int CTRL>
__device__ __forceinline__ float dpp_min(float v) {
    const int s = __float_as_int(v);
    const int r = __builtin_amdgcn_update_dpp(s, s, CTRL, 0xF, 0xF, false);
    return fminf(v, __int_as_float(r));
}
template<int CTRL>
__device__ __forceinline__ float dpp_max(float v) {
    const int s = __float_as_int(v);
    const int r = __builtin_amdgcn_update_dpp(s, s, CTRL, 0xF, 0xF, false);
    return fmaxf(v, __int_as_float(r));
}
// sum with lane-pair partner (quad_perm [1,0,3,2] = 0xB1): result in both lanes
__device__ __forceinline__ float pair_sum(float v) { return dpp_add<0xB1>(v); }
// full 64-lane reduce-to-all
__device__ __forceinline__ float wave64_sum(float v) {
    v = dpp_add<0x121>(v); v = dpp_add<0x122>(v);
    v = dpp_add<0x124>(v); v = dpp_add<0x128>(v);
    v += __shfl_xor(v, 16, 64);
    v += __shfl_xor(v, 32, 64);
    return v;
}
__device__ __forceinline__ float wave64_min(float v) {
    v = dpp_min<0x121>(v); v = dpp_min<0x122>(v);
    v = dpp_min<0x124>(v); v = dpp_min<0x128>(v);
    v = fminf(v, __shfl_xor(v, 16, 64));
    return fminf(v, __shfl_xor(v, 32, 64));
}
__device__ __forceinline__ float wave64_max(float v) {
    v = dpp_max<0x121>(v); v = dpp_max<0x122>(v);
    v = dpp_max<0x124>(v); v = dpp_max<0x128>(v);
    v = fmaxf(v, __shfl_xor(v, 16, 64));
    return fmaxf(v, __shfl_xor(v, 32, 64));
}

// Round-10: R9's ILP pair (two half-row matrices per wave) with the
// allocator UN-HINTED. Cross-round evidence: every min-waves hint round
// (R3/R5/R7/R9) clamped to <=64 VGPR and spilled (R9: 228 MB scratch
// writes); the plain-__launch_bounds__ round (R8) allocated 68 CLEAN.
// The hint sets a waves-per-EU range the backend serves by reg-capping
// even at spill cost. R9 proved the ILP mechanism works (VALU 73%) --
// this round removes the scratch tax:
//   (1) __launch_bounds__(TPB) -- no min-waves (R8-verified config)
//   (2) phase-2 column reads split A-loop then B-loop: peak pressure
//       ~16 outstanding loads + 32 acc regs instead of ~32 + 64.
// Phase 3/4 verbatim R9 (passed): HARD row guard (round-2 lesson),
// pre-masked LDS v/p (exact zeros), same-wave LDS producer/consumer,
// DPP reduces, 3-round 64-section Sturm.
__global__ __launch_bounds__(TPB)
void lap_main(const float* __restrict__ predA, const float* __restrict__ targA,
              const float* __restrict__ nmask, float* __restrict__ out,
              float* __restrict__ ws)
{
    __shared__ float  svA_[WPB][NB], svB_[WPB][NB];   // masked v (0 for r<=k)
    __shared__ float  spA_[WPB][NB], spB_[WPB][NB];   // masked p (0 for r<k)
    __shared__ float2 sdeA_[WPB][NB], sdeB_[WPB][NB]; // (d_r, e_{r-1}^2)
    __shared__ float  red[WPB][3];                    // bce, mask, phys

    const int t = threadIdx.x;            // 0..255
    const int w = t >> 6;                 // wave within block
    const int l = t & 63;                 // lane
    const int r = l >> 1;                 // row (0..31)
    const int h = l & 1;                  // column half (0..1)
    const int bA = blockIdx.x * MPB + w * 2;
    const int bB = bA + 1;
    const size_t baseA = (size_t)bA * (NB * NB);
    const size_t baseB = (size_t)bB * (NB * NB);

    // ---- phase 1: half-row loads + BCE partials, A then B ----
    const float mrA = nmask[(size_t)bA * NB + r];
    const float mrB = nmask[(size_t)bB * NB + r];
    const float4* prA = (const float4*)(predA + baseA + (size_t)r * NB + 16 * h);
    const float4* trA = (const float4*)(targA + baseA + (size_t)r * NB + 16 * h);
    const float4* nmA = (const float4*)(nmask + (size_t)bA * NB + 16 * h);
    const float4* prB = (const float4*)(predA + baseB + (size_t)r * NB + 16 * h);
    const float4* trB = (const float4*)(targA + baseB + (size_t)r * NB + 16 * h);
    const float4* nmB = (const float4*)(nmask + (size_t)bB * NB + 16 * h);

    float aA[16], aB[16];
    float accB = 0.f, accM = 0.f;
    #pragma unroll
    for (int q = 0; q < 4; ++q) {
        const float4 p  = prA[q];
        const float4 tg = trA[q];
        const float4 mc = nmA[q];
        const float bx = -(tg.x * __logf(p.x) + (1.f - tg.x) * __logf(1.f - p.x));
        const float by = -(tg.y * __logf(p.y) + (1.f - tg.y) * __logf(1.f - p.y));
        const float bz = -(tg.z * __logf(p.z) + (1.f - tg.z) * __logf(1.f - p.z));
        const float bw = -(tg.w * __logf(p.w) + (1.f - tg.w) * __logf(1.f - p.w));
        accB += mrA * (mc.x * bx + mc.y * by + mc.z * bz + mc.w * bw);
        accM += mrA * (mc.x + mc.y + mc.z + mc.w);
        aA[4*q+0] = p.x; aA[4*q+1] = p.y; aA[4*q+2] = p.z; aA[4*q+3] = p.w;
    }
    #pragma unroll
    for (int q = 0; q < 4; ++q) {
        const float4 p  = prB[q];
        const float4 tg = trB[q];
        const float4 mc = nmB[q];
        const float bx = -(tg.x * __logf(p.x) + (1.f - tg.x) * __logf(1.f - p.x));
        const float by = -(tg.y * __logf(p.y) + (1.f - tg.y) * __logf(1.f - p.y));
        const float bz = -(tg.z * __logf(p.z) + (1.f - tg.z) * __logf(1.f - p.z));
        const float bw = -(tg.w * __logf(p.w) + (1.f - tg.w) * __logf(1.f - p.w));
        accB += mrB * (mc.x * bx + mc.y * by + mc.z * bz + mc.w * bw);
        accM += mrB * (mc.x + mc.y + mc.z + mc.w);
        aB[4*q+0] = p.x; aB[4*q+1] = p.y; aB[4*q+2] = p.z; aB[4*q+3] = p.w;
    }

    // ---- phase 2: M = (L+L^T)/2 in place; A fully, then B (peak-pressure) ----
    const float jitter = 1e-5f + (9e-5f / 31.f) * (float)r;
    {
        float dsl = 0.f, pdl = 0.f;
        #pragma unroll
        for (int u = 0; u < 16; ++u) {
            dsl += aA[u];
            pdl = (16 * h + u == r) ? aA[u] : pdl;
        }
        const float dv = pair_sum(dsl) + jitter - pair_sum(pdl);
        #pragma unroll
        for (int u = 0; u < 16; ++u) {
            const int c = 16 * h + u;                           // global column
            const float cv = predA[baseA + (size_t)c * NB + r]; // P[c][r]
            aA[u] = (c == r) ? dv : -0.5f * (aA[u] + cv);
        }
    }
    {
        float dsl = 0.f, pdl = 0.f;
        #pragma unroll
        for (int u = 0; u < 16; ++u) {
            dsl += aB[u];
            pdl = (16 * h + u == r) ? aB[u] : pdl;
        }
        const float dv = pair_sum(dsl) + jitter - pair_sum(pdl);
        #pragma unroll
        for (int u = 0; u < 16; ++u) {
            const int c = 16 * h + u;
            const float cv = predA[baseB + (size_t)c * NB + r];
            aB[u] = (c == r) ? dv : -0.5f * (aB[u] + cv);
        }
    }

    // colk init: column 0 = A[r][0], owned by h==0 slot 0
    float colA, colB;
    {
        const float c0A = (h == 0) ? aA[0] : 0.f;
        const float c0B = (h == 0) ? aB[0] : 0.f;
        colA = pair_sum(c0A);
        colB = pair_sum(c0B);
    }

    // ---- phase 3: Householder, two interleaved independent chains ----
    float* svA = &svA_[w][0]; float* svB = &svB_[w][0];
    float* spA = &spA_[w][0]; float* spB = &spB_[w][0];
    const float4* vA4 = (const float4*)&svA[16 * h];
    const float4* vB4 = (const float4*)&svB[16 * h];
    const float4* pA4 = (const float4*)&spA[16 * h];
    const float4* pB4 = (const float4*)&spB[16 * h];
    for (int k = 0; k < NB - 2; ++k) {
        const float sgA = wave64_sum((h == 0 && r > k) ? colA * colA : 0.f);
        const float sgB = wave64_sum((h == 0 && r > k) ? colB * colB : 0.f);
        const float x1A = __shfl(colA, 2 * (k + 1), 64);
        const float x1B = __shfl(colB, 2 * (k + 1), 64);
        const float alA = (x1A >= 0.f) ? -sqrtf(sgA) : sqrtf(sgA);
        const float alB = (x1B >= 0.f) ? -sqrtf(sgB) : sqrtf(sgB);
        const float deA = sgA - alA * x1A;
        const float deB = sgB - alB * x1B;
        const float beA = (deA > 1e-30f) ? __builtin_amdgcn_rcpf(deA) : 0.f;
        const float beB = (deB > 1e-30f) ? __builtin_amdgcn_rcpf(deB) : 0.f;
        const float vjA = (r > k) ? (colA - ((r == k + 1) ? alA : 0.f)) : 0.f;
        const float vjB = (r > k) ? (colB - ((r == k + 1) ? alB : 0.f)) : 0.f;
        if (h == 0) { svA[r] = vjA; svB[r] = vjB; }  // pre-masked: 0 for r<=k

        // dots over my 16 cols via uniform-address b128 broadcasts
        float a0 = 0.f, a1 = 0.f, a2 = 0.f, a3 = 0.f;
        float b0 = 0.f, b1 = 0.f, b2 = 0.f, b3 = 0.f;
        #pragma unroll
        for (int q = 0; q < 4; ++q) {
            if (16 + 4 * q + 3 >= k) {      // wave-uniform conservative skip
                const float4 xA = vA4[q];
                const float4 xB = vB4[q];
                a0 += aA[4*q+0] * xA.x; a1 += aA[4*q+1] * xA.y;
                a2 += aA[4*q+2] * xA.z; a3 += aA[4*q+3] * xA.w;
                b0 += aB[4*q+0] * xB.x; b1 += aB[4*q+1] * xB.y;
                b2 += aB[4*q+2] * xB.z; b3 += aB[4*q+3] * xB.w;
            }
        }
        const float dotA = pair_sum((a0 + a1) + (a2 + a3));
        const float dotB = pair_sum((b0 + b1) + (b2 + b3));
        const float pjA = beA * dotA;
        const float pjB = beB * dotB;
        const float pmA = (r >= k) ? pjA : 0.f;
        const float pmB = (r >= k) ? pjB : 0.f;
        if (h == 0) { spA[r] = pmA; spB[r] = pmB; }
        const float KA = wave64_sum((h == 0) ? vjA * pmA : 0.f);
        const float KB = wave64_sum((h == 0) ? vjB * pmB : 0.f);
        const float s2A = pmA - 2.f * (0.5f * beA * KA) * vjA;
        const float s2B = pmB - 2.f * (0.5f * beB * KB) * vjB;
        const float nvA = -vjA, nsA = -s2A;
        const float nvB = -vjB, nsB = -s2B;

        // rank-2 updates under HARD row guard; v/p re-read from LDS
        float capA = 0.f, capB = 0.f;
        if (r >= k) {
            #pragma unroll
            for (int q = 0; q < 4; ++q) {
                if (16 + 4 * q + 3 >= k) {
                    const float4 xA = vA4[q]; const float4 pA = pA4[q];
                    const float4 xB = vB4[q]; const float4 pB = pB4[q];
                    #pragma unroll
                    for (int u = 0; u < 4; ++u) {
                        const int cl = 4 * q + u;
                        const float xvA = (u==0)?xA.x:(u==1)?xA.y:(u==2)?xA.z:xA.w;
                        const float pvA = (u==0)?pA.x:(u==1)?pA.y:(u==2)?pA.z:pA.w;
                        const float xvB = (u==0)?xB.x:(u==1)?xB.y:(u==2)?xB.z:xB.w;
                        const float pvB = (u==0)?pB.x:(u==1)?pB.y:(u==2)?pB.z:pB.w;
                        float vA = aA[cl];
                        vA = fmaf(nvA, pvA, vA);
                        vA = fmaf(nsA, xvA, vA);
                        aA[cl] = vA;
                        float vB = aB[cl];
                        vB = fmaf(nvB, pvB, vB);
                        vB = fmaf(nsB, xvB, vB);
                        aB[cl] = vB;
                        capA = (16 * h + cl == k + 1) ? vA : capA;
                        capB = (16 * h + cl == k + 1) ? vB : capB;
                    }
                }
            }
        }
        colA = pair_sum(capA);   // frozen rows get 0 (consumers mask r>k)
        colB = pair_sum(capB);
    }

    // ---- extraction: d_r = A[r][r], e_{r-1} = A[r][r-1] ----
    float dlA = 0.f, elA = 0.f, dlB = 0.f, elB = 0.f;
    #pragma unroll
    for (int u = 0; u < 16; ++u) {
        dlA = (16 * h + u == r)     ? aA[u] : dlA;
        elA = (16 * h + u == r - 1) ? aA[u] : elA;
        dlB = (16 * h + u == r)     ? aB[u] : dlB;
        elB = (16 * h + u == r - 1) ? aB[u] : elB;
    }
    const float dA = pair_sum(dlA);
    const float eA = pair_sum(elA);
    const float dB = pair_sum(dlB);
    const float eB = pair_sum(elB);
    if (h == 0) { sdeA_[w][r] = make_float2(dA, eA * eA);
                  sdeB_[w][r] = make_float2(dB, eB * eB); }

    // Gershgorin bounds (pair-duplicated values are harmless for min/max)
    const float aeA = fabsf(eA), aeB = fabsf(eB);
    const float anA = (r == 31) ? 0.f : __shfl(aeA, (l + 2) & 63, 64);
    const float anB = (r == 31) ? 0.f : __shfl(aeB, (l + 2) & 63, 64);
    float loA = wave64_min(dA - (aeA + anA));
    float hiA = wave64_max(dA + (aeA + anA));
    float loB = wave64_min(dB - (aeB + anB));
    float hiB = wave64_max(dB + (aeB + anB));

    // ---- phase 4: Sturm multisection, interleaved chains, 64 sigmas ----
    const float2* deA = (const float2*)&sdeA_[w][0];
    const float2* deB = (const float2*)&sdeB_[w][0];
    for (int round = 0; round < 3; ++round) {
        asm volatile("" ::: "memory");   // no cross-round CSE of LDS loads
        const float stA = (hiA - loA) * (1.f / 65.f);
        const float stB = (hiB - loB) * (1.f / 65.f);
        const float siA = loA + stA * (float)(l + 1);
        const float siB = loB + stB * (float)(l + 1);
        float qA = deA[0].x - siA;
        float qB = deB[0].x - siB;
        int cA = (qA < 0.f), cB = (qB < 0.f);
        #pragma unroll
        for (int i = 1; i < NB; ++i) {
            const float2 diA = deA[i];
            const float2 diB = deB[i];
            if (fabsf(qA) < 1e-20f) qA = (qA < 0.f) ? -1e-20f : 1e-20f;
            if (fabsf(qB) < 1e-20f) qB = (qB < 0.f) ? -1e-20f : 1e-20f;
            qA = (diA.x - siA) - diA.y * __builtin_amdgcn_rcpf(qA);
            qB = (diB.x - siB) - diB.y * __builtin_amdgcn_rcpf(qB);
            cA += (qA < 0.f);
            cB += (qB < 0.f);
        }
        const unsigned long long balA = __ballot(cA >= 2);
        const unsigned long long balB = __ballot(cB >= 2);
        const int jsA = (balA == 0ull) ? 64 : __builtin_ctzll(balA);
        const int jsB = (balB == 0ull) ? 64 : __builtin_ctzll(balB);
        const float nlA = loA + stA * (float)jsA;
        const float nhA = loA + stA * (float)(jsA + 1);
        const float nlB = loB + stB * (float)jsB;
        const float nhB = loB + stB * (float)(jsB + 1);
        loA = nlA; hiA = nhA; loB = nlB; hiB = nhB;
    }
    const float lamA = 0.5f * (loA + hiA);
    const float lamB = 0.5f * (loB + hiB);

    if (l == 0) { out[2 + bA] = lamA; out[2 + bB] = lamB; }

    // ---- final: per-wave reduce + 3 atomics per block ----
    const float accBs = wave64_sum(accB);
    const float accMs = wave64_sum(accM);
    const float ph = fmaxf(0.1f - lamA, 0.f) + fmaxf(0.1f - lamB, 0.f);
    if (l == 0) { red[w][0] = accBs; red[w][1] = accMs; red[w][2] = ph; }
    __syncthreads();
    if (t == 0) {
        float sB = 0.f, sM = 0.f, sP = 0.f;
        #pragma unroll
        for (int i = 0; i < WPB; ++i) { sB += red[i][0]; sM += red[i][1]; sP += red[i][2]; }
        atomicAdd(ws + 0, sB);
        atomicAdd(ws + 1, sM);
        atomicAdd(ws + 2, sP);
    }
}

__global__ __launch_bounds__(64)
void lap_final(float* __restrict__ out, const float* __restrict__ ws) {
    if (threadIdx.x == 0) {
        out[0] = ws[0] / fmaxf(ws[1], 1.f);
        out[1] = ws[2] * (1.f / (float)BATCH);
    }
}

extern "C" void kernel_launch(void* const* d_in, const int* in_sizes, int n_in,
                              void* d_out, int out_size, void* d_ws, size_t ws_size,
                              hipStream_t stream) {
    const float* pred = (const float*)d_in[0];
    const float* targ = (const float*)d_in[1];
    const float* nm   = (const float*)d_in[2];
    float* out = (float*)d_out;
    float* ws  = (float*)d_ws;

    (void)hipMemsetAsync(d_ws, 0, 16, stream);
    hipLaunchKernelGGL(lap_main, dim3(BATCH / MPB), dim3(TPB), 0, stream,
                       pred, targ, nm, out, ws);
    hipLaunchKernelGGL(lap_final, dim3(1), dim3(64), 0, stream, out, ws);
}